// Round 11
// baseline (376.392 us; speedup 1.0000x reference)
//
#include <hip/hip_runtime.h>

#define N_NODES 25600
#define N_EDGES 409600
#define EPSV 1e-5f

__device__ __forceinline__ unsigned short f2bf(float f) {
    unsigned int x = __float_as_uint(f);
    x += 0x7fffu + ((x >> 16) & 1u);
    return (unsigned short)(x >> 16);
}
// packed 2x f32 -> bf16x2 in one instruction where available (gfx950: v_cvt_pk_bf16_f32)
__device__ __forceinline__ unsigned int f2bf2(float a, float b) {
#if __has_builtin(__builtin_amdgcn_cvt_pk_bf16_f32)
    auto r = __builtin_amdgcn_cvt_pk_bf16_f32(a, b);
    unsigned int u;
    __builtin_memcpy(&u, &r, 4);
    return u;
#else
    return (unsigned int)f2bf(a) | ((unsigned int)f2bf(b) << 16);
#endif
}

using frag_ab = __attribute__((ext_vector_type(8))) short;  // 8 bf16 = 4 VGPRs
using frag_cd = __attribute__((ext_vector_type(4))) float;
typedef _Float16 f16x8 __attribute__((ext_vector_type(8))); // 8 f16 = 4 VGPRs

#define TWST 72   // transform weight LDS stride (bf16)
#define THST 200  // transform h/y1 LDS stride (bf16)

// ---------------- fused transform: x[n,0:96] = W2g·prelu(W1g·h[n]+b1)+b2, grouped, MFMA ----------------
__global__ __launch_bounds__(256) void transform_mfma(
    const float* __restrict__ h,
    const float* __restrict__ tpw1, const float* __restrict__ tpb1, const float* __restrict__ tpa,
    const float* __restrict__ tpw2, const float* __restrict__ tpb2,
    const float* __restrict__ tmw1, const float* __restrict__ tmb1, const float* __restrict__ tma,
    const float* __restrict__ tmw2, const float* __restrict__ tmb2,
    float* __restrict__ xout, _Float16* __restrict__ xh)
{
    __shared__ alignas(16) unsigned short W1s[192 * TWST]; // [o][i] bf16
    __shared__ alignas(16) unsigned short W2s[96 * TWST];  // [o][i] bf16
    __shared__ alignas(16) unsigned short hs[64 * THST];   // [m][c] bf16; y1 overwrites in place
    __shared__ float b1s[192];
    __shared__ float b2s[96];

    const int tid = threadIdx.x;
    const int s = blockIdx.y;
    const float* w1 = s ? tmw1 : tpw1;
    const float* b1 = s ? tmb1 : tpb1;
    const float* w2 = s ? tmw2 : tpw2;
    const float* b2 = s ? tmb2 : tpb2;
    const float alpha = (s ? tma : tpa)[0];

    #pragma unroll
    for (int r = 0; r < 12; r++) {
        int idx4 = r * 256 + tid;                    // over 192*16
        int o = idx4 >> 4, i4 = (idx4 & 15) * 4;
        const float4 a = *(const float4*)&w1[o * 64 + i4];
        *(uint2*)&W1s[o * TWST + i4] = make_uint2(f2bf2(a.x, a.y), f2bf2(a.z, a.w));
    }
    #pragma unroll
    for (int r = 0; r < 6; r++) {
        int idx4 = r * 256 + tid;                    // over 96*16
        int o = idx4 >> 4, i4 = (idx4 & 15) * 4;
        const float4 a = *(const float4*)&w2[o * 64 + i4];
        *(uint2*)&W2s[o * TWST + i4] = make_uint2(f2bf2(a.x, a.y), f2bf2(a.z, a.w));
    }
    if (tid < 192) b1s[tid] = b1[tid];
    if (tid < 96) b2s[tid] = b2[tid];
    __syncthreads();

    const int lane = tid & 63;
    const int wv = tid >> 6;
    const int quad = lane >> 4;
    const int lcol = lane & 15;
    const int m0 = wv * 16;
    const int j0 = blockIdx.x * 64;

    #pragma unroll
    for (int r = 0; r < 12; r++) {
        int idx = r * 256 + tid;                     // over 64*48 float4s
        int m = idx / 48, q = idx - m * 48;
        const float4 a = *(const float4*)&h[(2 * (j0 + m) + s) * 192 + q * 4];
        *(uint2*)&hs[m * THST + q * 4] = make_uint2(f2bf2(a.x, a.y), f2bf2(a.z, a.w));
    }
    __syncthreads();

    const int arow = (m0 + lcol) * THST;
    #pragma unroll
    for (int g = 0; g < 3; g++) {
        frag_cd acc[4];
        #pragma unroll
        for (int nt = 0; nt < 4; nt++) acc[nt] = (frag_cd){0.f, 0.f, 0.f, 0.f};
        #pragma unroll
        for (int kt = 0; kt < 2; kt++) {
            const int k0 = kt * 32 + quad * 8;
            frag_ab af = *(const frag_ab*)&hs[arow + g * 64 + k0];
            #pragma unroll
            for (int nt = 0; nt < 4; nt++) {
                frag_ab bf = *(const frag_ab*)&W1s[(g * 64 + nt * 16 + lcol) * TWST + k0];
                acc[nt] = __builtin_amdgcn_mfma_f32_16x16x32_bf16(af, bf, acc[nt], 0, 0, 0);
            }
        }
        #pragma unroll
        for (int nt = 0; nt < 4; nt++) {
            const int o = g * 64 + nt * 16 + lcol;
            const float bv = b1s[o];
            #pragma unroll
            for (int reg = 0; reg < 4; reg++) {
                float u = acc[nt][reg] + bv;
                u = u >= 0.f ? u : alpha * u;
                hs[(m0 + quad * 4 + reg) * THST + o] = f2bf(u);
            }
        }
    }
    #pragma unroll
    for (int g2 = 0; g2 < 3; g2++) {
        frag_cd acc[2];
        acc[0] = (frag_cd){0.f, 0.f, 0.f, 0.f};
        acc[1] = (frag_cd){0.f, 0.f, 0.f, 0.f};
        #pragma unroll
        for (int kt = 0; kt < 2; kt++) {
            const int k0 = kt * 32 + quad * 8;
            frag_ab af = *(const frag_ab*)&hs[arow + g2 * 64 + k0];
            #pragma unroll
            for (int nt = 0; nt < 2; nt++) {
                frag_ab bf = *(const frag_ab*)&W2s[(g2 * 32 + nt * 16 + lcol) * TWST + k0];
                acc[nt] = __builtin_amdgcn_mfma_f32_16x16x32_bf16(af, bf, acc[nt], 0, 0, 0);
            }
        }
        #pragma unroll
        for (int nt = 0; nt < 2; nt++) {
            const int o2 = g2 * 32 + nt * 16 + lcol;
            const float bv = b2s[o2];
            #pragma unroll
            for (int reg = 0; reg < 4; reg++) {
                const int node = 2 * (j0 + m0 + quad * 4 + reg) + s;
                const float v = acc[nt][reg] + bv;
                xout[node * 96 + o2] = v;
                xh[node * 96 + o2] = (_Float16)v;
            }
        }
    }
}

// ---------------- gate device body (round-5 proven structure; W1 fragments read directly from
// global frag-major gw1f — coalesced 1KB/wave reads of a 36KB L2-resident table, like final_body.
// Zero LDS, zero barriers -> occupancy capped by VGPR only; waves free-run. ----------------
template<bool DUAL>
__device__ __forceinline__ void gate_body(
    const _Float16* __restrict__ xh,
    const _Float16* __restrict__ W1fA, const _Float16* __restrict__ W1fB,
    const int* __restrict__ srcp, const int* __restrict__ dstp,
    const int* __restrict__ mapA,
    const float* __restrict__ gb1, const float* __restrict__ ga,
    const float* __restrict__ gW2, const float* __restrict__ gb2,
    int layerA, int layerB, int gid,
    float* __restrict__ outA, float* __restrict__ outB)
{
    const int tid  = threadIdx.x;
    const int lane = tid & 63;
    const int wv   = tid >> 6;
    const int quad = lane >> 4;
    const int lcol = lane & 15;
    const int m0   = wv * 16;
    const int erow = m0 + lcol;
    const int koff = quad * 8;

    // tile-invariant per-lane W2/b1 (indexed by o = nt*16+lcol)
    float w2A[6], b1A[6], w2B[6], b1B[6];
    #pragma unroll
    for (int nt = 0; nt < 6; nt++) {
        w2A[nt] = gW2[layerA * 96 + nt * 16 + lcol];
        b1A[nt] = gb1[layerA * 96 + nt * 16 + lcol];
        if (DUAL) {
            w2B[nt] = gW2[layerB * 96 + nt * 16 + lcol];
            b1B[nt] = gb1[layerB * 96 + nt * 16 + lcol];
        }
    }
    const float alphaA = ga[layerA];
    const float b2A = gb2[layerA];
    const float alphaB = DUAL ? ga[layerB] : 0.f;
    const float b2B = DUAL ? gb2[layerB] : 0.f;

    // slot indices for this lane's edge in each of the 4 group-contiguous tiles
    int si[4], di[4];
    #pragma unroll
    for (int t = 0; t < 4; t++) {
        const int s = gid * 256 + t * 64 + erow;
        si[t] = srcp[s];
        di[t] = dstp[s];
    }

    // preload tile 0's six 16B row chunks
    f16x8 A0, A1, A2, B0, B1, B2;
    {
        const _Float16* rs = xh + si[0] * 96 + koff;
        const _Float16* rd = xh + di[0] * 96 + koff;
        A0 = *(const f16x8*)rs;        B0 = *(const f16x8*)rd;
        A1 = *(const f16x8*)(rs + 32); B1 = *(const f16x8*)(rd + 32);
        A2 = *(const f16x8*)(rs + 64); B2 = *(const f16x8*)(rd + 64);
    }

    #pragma unroll
    for (int t = 0; t < 4; t++) {
        // products (v_pk_mul_f16) = this tile's A-fragments
        f16x8 p0 = A0 * B0;
        f16x8 p1 = A1 * B1;
        f16x8 p2 = A2 * B2;
        // issue next tile's gathers before the MFMA cluster (latency hides under compute)
        if (t < 3) {
            const _Float16* rs = xh + si[t + 1] * 96 + koff;
            const _Float16* rd = xh + di[t + 1] * 96 + koff;
            A0 = *(const f16x8*)rs;        B0 = *(const f16x8*)rd;
            A1 = *(const f16x8*)(rs + 32); B1 = *(const f16x8*)(rd + 32);
            A2 = *(const f16x8*)(rs + 64); B2 = *(const f16x8*)(rd + 64);
        }

        frag_cd accA[6], accB[6];
        #pragma unroll
        for (int nt = 0; nt < 6; nt++) {
            accA[nt] = (frag_cd){0.f, 0.f, 0.f, 0.f};
            if (DUAL) accB[nt] = (frag_cd){0.f, 0.f, 0.f, 0.f};
        }
        __builtin_amdgcn_s_setprio(1);
        #pragma unroll
        for (int kt = 0; kt < 3; kt++) {
            const f16x8 pk = (kt == 0) ? p0 : (kt == 1 ? p1 : p2);
            #pragma unroll
            for (int nt = 0; nt < 6; nt++) {
                const int f = ((nt * 3 + kt) * 4 + quad) * 16 + lcol;
                f16x8 bfragA = *(const f16x8*)&W1fA[f * 8];
                accA[nt] = __builtin_amdgcn_mfma_f32_16x16x32_f16(pk, bfragA, accA[nt], 0, 0, 0);
                if (DUAL) {
                    f16x8 bfragB = *(const f16x8*)&W1fB[f * 8];
                    accB[nt] = __builtin_amdgcn_mfma_f32_16x16x32_f16(pk, bfragB, accB[nt], 0, 0, 0);
                }
            }
        }
        __builtin_amdgcn_s_setprio(0);
        // phase 3: +b1, prelu, dot W2 (registers). C/D: col=lcol (o), row=quad*4+reg (edge).
        float psA[4] = {0.f, 0.f, 0.f, 0.f};
        float psB[4] = {0.f, 0.f, 0.f, 0.f};
        #pragma unroll
        for (int nt = 0; nt < 6; nt++) {
            #pragma unroll
            for (int reg = 0; reg < 4; reg++) {
                float u = accA[nt][reg] + b1A[nt];
                u = u >= 0.f ? u : alphaA * u;
                psA[reg] += u * w2A[nt];
            }
            if (DUAL) {
                #pragma unroll
                for (int reg = 0; reg < 4; reg++) {
                    float u = accB[nt][reg] + b1B[nt];
                    u = u >= 0.f ? u : alphaB * u;
                    psB[reg] += u * w2B[nt];
                }
            }
        }
        // shortened reduce over lcol: 2 stages x 4 regs -> reg-select (lcol&3) -> 2 stages x 1
        #pragma unroll
        for (int off = 1; off < 4; off <<= 1) {
            #pragma unroll
            for (int reg = 0; reg < 4; reg++) {
                psA[reg] += __shfl_xor(psA[reg], off, 64);
                if (DUAL) psB[reg] += __shfl_xor(psB[reg], off, 64);
            }
        }
        float vA = (lcol & 2) ? ((lcol & 1) ? psA[3] : psA[2])
                              : ((lcol & 1) ? psA[1] : psA[0]);
        vA += __shfl_xor(vA, 4, 64);
        vA += __shfl_xor(vA, 8, 64);
        float vB = 0.f;
        if (DUAL) {
            vB = (lcol & 2) ? ((lcol & 1) ? psB[3] : psB[2])
                            : ((lcol & 1) ? psB[1] : psB[0]);
            vB += __shfl_xor(vB, 4, 64);
            vB += __shfl_xor(vB, 8, 64);
        }
        // tanh on all lanes (no divergence); 16 lanes store (4B each, quad-consecutive)
        const float eA = tanhf(vA + b2A);
        const float eB = DUAL ? tanhf(vB + b2B) : 0.f;
        if (lcol < 4) {
            const int slot = gid * 256 + t * 64 + m0 + quad * 4 + lcol;
            outA[mapA ? mapA[slot] : slot] = eA;
            if (DUAL) outB[slot] = eB;
        }
    }
}

// ---------------- gate kernel: LDS-free, W1 fragments straight from global gw1f ----------------
template<bool DUAL>
__global__ __launch_bounds__(256) void gate_kernel(
    const _Float16* __restrict__ xh,
    const int* __restrict__ srcp, const int* __restrict__ dstp,
    const int* __restrict__ mapA,
    const _Float16* __restrict__ gw1f, const float* __restrict__ gb1,
    const float* __restrict__ ga,  const float* __restrict__ gW2,
    const float* __restrict__ gb2, int layerA, int layerB,
    float* __restrict__ outA, float* __restrict__ outB)
{
    gate_body<DUAL>(xh, gw1f + layerA * 9216, gw1f + layerB * 9216,
                    srcp, dstp, mapA, gb1, ga, gW2, gb2,
                    layerA, layerB, blockIdx.x, outA, outB);
}

// ---------------- CSR build: count / scan / scatter ----------------
__global__ __launch_bounds__(256) void count_kernel(
    const int* __restrict__ dst, int* __restrict__ cnt)
{
    int e = blockIdx.x * 256 + threadIdx.x;          // over E, exact
    atomicAdd(&cnt[dst[e]], 1);
}

// single block, 1024 threads; 25600 = 1024 * 25
__global__ __launch_bounds__(1024) void scan_kernel(
    const int* __restrict__ cnt, int* __restrict__ off, int* __restrict__ cur)
{
    __shared__ int part[1024];
    const int tid = threadIdx.x;
    const int base = tid * 25;
    int loc[25];
    int s = 0;
    #pragma unroll
    for (int i = 0; i < 25; i++) { loc[i] = s; s += cnt[base + i]; }
    part[tid] = s;
    __syncthreads();
    for (int d = 1; d < 1024; d <<= 1) {
        int t = (tid >= d) ? part[tid - d] : 0;
        __syncthreads();
        part[tid] += t;
        __syncthreads();
    }
    const int basesum = part[tid] - s;
    #pragma unroll
    for (int i = 0; i < 25; i++) {
        int o = basesum + loc[i];
        off[base + i] = o;
        cur[base + i] = o;
    }
    if (tid == 1023) off[N_NODES] = part[1023];
}

// also emits slot-ordered srcp/dstp so the gate and agg skip the perm indirection
__global__ __launch_bounds__(256) void scatter_kernel(
    const int* __restrict__ dst, const int* __restrict__ src,
    int* __restrict__ cur, int* __restrict__ perm,
    int* __restrict__ srcp, int* __restrict__ dstp)
{
    int e = blockIdx.x * 256 + threadIdx.x;          // over E, exact
    int d = dst[e];
    int p = atomicAdd(&cur[d], 1);
    perm[p] = e;
    srcp[p] = src[e];
    dstp[p] = d;
}

// ---------------- prep: t2wf = frag-major f16 transpose of t2w ----------------
__global__ __launch_bounds__(256) void prep_t2w(
    const float* __restrict__ t2w, _Float16* __restrict__ t2wf)
{
    int idx = blockIdx.x * 256 + threadIdx.x;        // over 36864, exact (144 blocks)
    int j = idx & 7;
    int t = idx >> 3;
    int lc = t & 15;
    int u = t >> 4;
    int c = u % 36, nt = u / 36;
    int o = nt * 16 + lc;
    int ck = c / 12, r = c - ck * 12;
    int kt3 = r >> 2, quad = r & 3;
    int k = ck * 96 + kt3 * 32 + quad * 8 + j;
    t2wf[idx] = (_Float16)t2w[k * 128 + o];
}

// ---------------- prep: gw1f = frag-major f16 gate W1 for both layers ----------------
__global__ __launch_bounds__(256) void prep_gw1(
    const float* __restrict__ gW1, _Float16* __restrict__ gw1f)
{
    int idx = blockIdx.x * 256 + threadIdx.x;        // over 2*9216, exact (72 blocks)
    int layer = idx / 9216;
    int rem = idx - layer * 9216;
    int fi = rem >> 3, j = rem & 7;
    int lc = fi & 15, r = fi >> 4;
    int quad = r & 3, t3 = r >> 2;
    int nt = t3 / 3, kt = t3 - nt * 3;
    int n = nt * 16 + lc, k0 = kt * 32 + quad * 8;
    gw1f[idx] = (_Float16)gW1[layer * 9216 + (k0 + j) * 96 + n];
}

// ---------------- fused: z = segsum(x[src]*e, dst) ; x_next = prelu(BN(LN(z + xin))) ----------------
// Gathers the f16 mirror xg (192B rows); residual xin stays f32; all accumulation f32.
// 8 independent gather chains in flight. Wave butterflies + 2-slot LDS combine (2 barriers).
__global__ __launch_bounds__(128) void agg_norm_kernel(
    const _Float16* __restrict__ xg, const int* __restrict__ srcp,
    const float* __restrict__ ef,
    const int* __restrict__ off,
    const float* __restrict__ xin,
    const float* __restrict__ lng, const float* __restrict__ lnb,
    const float* __restrict__ bng, const float* __restrict__ bnb,
    const float* __restrict__ bnrm, const float* __restrict__ bnrv,
    const float* __restrict__ acta, int layer,
    float* __restrict__ xout, _Float16* __restrict__ xh)
{
    __shared__ float red[4];                 // [0..1]=per-wave sum, [2..3]=per-wave var
    const int n = blockIdx.x;
    const int tid = threadIdx.x;
    const int wv = tid >> 6;
    const int beg = off[n], end = off[n + 1];
    float v = 0.f;
    if (tid < 96) {
        float v0 = 0.f, v1 = 0.f, v2 = 0.f, v3 = 0.f;
        float v4 = 0.f, v5 = 0.f, v6 = 0.f, v7 = 0.f;
        int j = beg;
        for (; j + 8 <= end; j += 8) {
            v0 += (float)xg[srcp[j]     * 96 + tid] * ef[j];
            v1 += (float)xg[srcp[j + 1] * 96 + tid] * ef[j + 1];
            v2 += (float)xg[srcp[j + 2] * 96 + tid] * ef[j + 2];
            v3 += (float)xg[srcp[j + 3] * 96 + tid] * ef[j + 3];
            v4 += (float)xg[srcp[j + 4] * 96 + tid] * ef[j + 4];
            v5 += (float)xg[srcp[j + 5] * 96 + tid] * ef[j + 5];
            v6 += (float)xg[srcp[j + 6] * 96 + tid] * ef[j + 6];
            v7 += (float)xg[srcp[j + 7] * 96 + tid] * ef[j + 7];
        }
        for (; j < end; j++) {
            v0 += (float)xg[srcp[j] * 96 + tid] * ef[j];
        }
        v = (((v0 + v1) + (v2 + v3)) + ((v4 + v5) + (v6 + v7))) + xin[n * 96 + tid];
    }
    float r = v;
    #pragma unroll
    for (int o2 = 1; o2 < 64; o2 <<= 1) r += __shfl_xor(r, o2, 64);
    if ((tid & 63) == 0) red[wv] = r;
    __syncthreads();
    const float mean = (red[0] + red[1]) * (1.f / 96.f);
    const float d = (tid < 96) ? (v - mean) : 0.f;
    float r2 = d * d;
    #pragma unroll
    for (int o2 = 1; o2 < 64; o2 <<= 1) r2 += __shfl_xor(r2, o2, 64);
    if ((tid & 63) == 0) red[2 + wv] = r2;
    __syncthreads();
    const float rstd = rsqrtf((red[2] + red[3]) * (1.f / 96.f) + EPSV);
    if (tid < 96) {
        const int c = layer * 96 + tid;
        float y = d * rstd * lng[c] + lnb[c];
        y = (y - bnrm[c]) * rsqrtf(bnrv[c] + EPSV) * bng[c] + bnb[c];
        const float a = acta[layer];
        const float o = y >= 0.f ? y : a * y;
        if (xout) xout[n * 96 + tid] = o;
        xh[n * 96 + tid] = (_Float16)o;
    }
}

// ---------------- final device body: out[64-node tile] = hcat @ t2_w + t2_b (MFMA, K=288) ----------------
__device__ __forceinline__ void final_body(
    const _Float16* __restrict__ xh0, const _Float16* __restrict__ xh1,
    const _Float16* __restrict__ xh2, const _Float16* __restrict__ t2wf,
    const float* __restrict__ t2b, float* __restrict__ out, int bid)
{
    const int tid  = threadIdx.x;
    const int lane = tid & 63;
    const int wv   = tid >> 6;
    const int quad = lane >> 4;
    const int lcol = lane & 15;
    const int mrow = bid * 64 + wv * 16 + lcol;

    frag_cd acc[8];
    #pragma unroll
    for (int nt = 0; nt < 8; nt++) acc[nt] = (frag_cd){0.f, 0.f, 0.f, 0.f};

    #pragma unroll
    for (int ck = 0; ck < 3; ck++) {
        const _Float16* xc = (ck == 0) ? xh0 : (ck == 1 ? xh1 : xh2);
        const _Float16* ap = xc + mrow * 96 + quad * 8;
        #pragma unroll
        for (int kt3 = 0; kt3 < 3; kt3++) {
            f16x8 afrag = *(const f16x8*)(ap + kt3 * 32);
            const int chunk = 12 * ck + 4 * kt3 + quad;
            #pragma unroll
            for (int nt = 0; nt < 8; nt++) {
                f16x8 bfrag = *(const f16x8*)&t2wf[((nt * 36 + chunk) * 16 + lcol) * 8];
                acc[nt] = __builtin_amdgcn_mfma_f32_16x16x32_f16(afrag, bfrag, acc[nt], 0, 0, 0);
            }
        }
    }
    const int node = bid * 64 + wv * 16 + quad * 4;
    #pragma unroll
    for (int nt = 0; nt < 8; nt++) {
        const int o = nt * 16 + lcol;
        const float bias = t2b[o];
        #pragma unroll
        for (int reg = 0; reg < 4; reg++)
            out[(node + reg) * 128 + o] = acc[nt][reg] + bias;
    }
}

// ---------------- fused tail: gate(layer1 es -> ee1) interleaved 4:1 with final readout ----------------
__global__ __launch_bounds__(256) void gate_final_kernel(
    const _Float16* __restrict__ xh0, const _Float16* __restrict__ xh1,
    const _Float16* __restrict__ xh2,
    const int* __restrict__ srcp, const int* __restrict__ dstp,
    const int* __restrict__ perm,
    const _Float16* __restrict__ gw1f, const float* __restrict__ gb1,
    const float* __restrict__ ga,  const float* __restrict__ gW2,
    const float* __restrict__ gb2,
    const _Float16* __restrict__ t2wf, const float* __restrict__ t2b,
    float* __restrict__ ee1, float* __restrict__ out)
{
    const int g = blockIdx.x / 5;
    const int pos = blockIdx.x - g * 5;
    if (pos < 4) {
        gate_body<false>(xh2, gw1f + 9216, gw1f + 9216, srcp, dstp, perm,
                         gb1, ga, gW2, gb2, 1, 0, g * 4 + pos, ee1, nullptr);
    } else {
        final_body(xh0, xh1, xh2, t2wf, t2b, out, g);
    }
}

extern "C" void kernel_launch(void* const* d_in, const int* in_sizes, int n_in,
                              void* d_out, int out_size, void* d_ws, size_t ws_size,
                              hipStream_t stream)
{
    const float* h    = (const float*)d_in[0];
    const int*   src  = (const int*)d_in[1];
    const int*   dst  = (const int*)d_in[2];
    const float* tpw1 = (const float*)d_in[3];
    const float* tpb1 = (const float*)d_in[4];
    const float* tpa  = (const float*)d_in[5];
    const float* tpw2 = (const float*)d_in[6];
    const float* tpb2 = (const float*)d_in[7];
    const float* tmw1 = (const float*)d_in[8];
    const float* tmb1 = (const float*)d_in[9];
    const float* tma  = (const float*)d_in[10];
    const float* tmw2 = (const float*)d_in[11];
    const float* tmb2 = (const float*)d_in[12];
    const float* lng  = (const float*)d_in[13];
    const float* lnb  = (const float*)d_in[14];
    const float* bng  = (const float*)d_in[15];
    const float* bnb  = (const float*)d_in[16];
    const float* bnrm = (const float*)d_in[17];
    const float* bnrv = (const float*)d_in[18];
    const float* acta = (const float*)d_in[19];
    const float* gW1  = (const float*)d_in[20];
    const float* gb1  = (const float*)d_in[21];
    const float* ga   = (const float*)d_in[22];
    const float* gW2  = (const float*)d_in[23];
    const float* gb2  = (const float*)d_in[24];
    const float* t2w  = (const float*)d_in[25];
    const float* t2b  = (const float*)d_in[26];

    // workspace layout: byte-identical footprint to the round-2/5/8/9/10 passing layout (~41.27 MB).
    float* ws = (float*)d_ws;
    float* x0 = ws;                         // N*96 f32 (agg0 residual)
    float* x1 = x0 + N_NODES * 96;          // N*96 f32 (agg1 residual)
    float* eb = x1 + N_NODES * 96;          // E f32 (slot order)
    _Float16* xh0 = (_Float16*)(eb + N_EDGES);      // N*96 f16 mirror (stage 0)
    _Float16* xh1 = xh0 + N_NODES * 96;             // N*96 f16 mirror (stage 1)
    _Float16* xh2 = xh1 + N_NODES * 96;             // N*96 f16 mirror (stage 2)
    int* cnt  = (int*)(xh2 + N_NODES * 96); // N   (dead after scatter)
    int* off  = cnt + N_NODES;              // N+1
    int* cur  = off + N_NODES + 1;          // N   (dead after scatter)
    int* perm = cur + N_NODES;              // E   (slot -> original edge)
    int* srcp = perm + N_EDGES;             // E   (slot-ordered src)
    int* dstp = srcp + N_EDGES;             // E   (slot-ordered dst)
    // t2wf aliases cnt (73,728 B < 102,400 B), gw1f aliases cur (36,864 B < 102,400 B):
    // both written AFTER scatter_kernel, when cnt/cur are dead. Stream order guarantees safety.
    _Float16* t2wf = (_Float16*)cnt;        // 36864 f16 (frag-major readout weight)
    _Float16* gw1f = (_Float16*)cur;        // 2*9216 f16 (frag-major gate W1, both layers)

    float* out = (float*)d_out;             // N*128 fp32
    float* ee  = out + N_NODES * 128;       // 2E fp32

    // ---- CSR build (dst-only; used by gate + agg_norm) ----
    hipMemsetAsync(cnt, 0, N_NODES * sizeof(int), stream);
    count_kernel<<<N_EDGES / 256, 256, 0, stream>>>(dst, cnt);
    scan_kernel<<<1, 1024, 0, stream>>>(cnt, off, cur);
    scatter_kernel<<<N_EDGES / 256, 256, 0, stream>>>(dst, src, cur, perm, srcp, dstp);
    // cnt/cur now dead -> reuse for prepped weights
    prep_t2w<<<144, 256, 0, stream>>>(t2w, t2wf);
    prep_gw1<<<72, 256, 0, stream>>>(gW1, gw1f);

    // ---- fused transform (t1+t2): x0 fp32 + xh0 = f16(x0) ----
    transform_mfma<<<dim3(200, 2), 256, 0, stream>>>(
        h, tpw1, tpb1, tpa, tpw2, tpb2, tmw1, tmb1, tma, tmw2, tmb2, x0, xh0);

    // ---- layer 0 ----
    gate_kernel<false><<<1600, 256, 0, stream>>>(xh0, srcp, dstp, nullptr,
        gw1f, gb1, ga, gW2, gb2, 0, 0, eb, nullptr);
    agg_norm_kernel<<<N_NODES, 128, 0, stream>>>(xh0, srcp, eb, off, x0,
        lng, lnb, bng, bnb, bnrm, bnrv, acta, 0, x1, xh1);  // gather f16 xh0; residual f32 x0

    // ---- fused: es[layer0](x1) -> ee (orig order)  AND  agg-gate[layer1](x1) -> eb (slot order) ----
    gate_kernel<true><<<1600, 256, 0, stream>>>(xh1, srcp, dstp, perm,
        gw1f, gb1, ga, gW2, gb2, 0, 1, ee, eb);

    // ---- layer 1 ----
    agg_norm_kernel<<<N_NODES, 128, 0, stream>>>(xh1, srcp, eb, off, x1,
        lng, lnb, bng, bnb, bnrm, bnrv, acta, 1, nullptr, xh2);  // gather f16 xh1; residual f32 x1

    // ---- fused tail: es[layer1](xh2) -> ee+E  interleaved with readout ----
    gate_final_kernel<<<2000, 256, 0, stream>>>(xh0, xh1, xh2, srcp, dstp, perm,
        gw1f, gb1, ga, gW2, gb2, t2wf, t2b, ee + N_EDGES, out);
}

// Round 12
// 348.623 us; speedup vs baseline: 1.0797x; 1.0797x over previous
//
#include <hip/hip_runtime.h>

#define N_NODES 25600
#define N_EDGES 409600
#define EPSV 1e-5f

__device__ __forceinline__ unsigned short f2bf(float f) {
    unsigned int x = __float_as_uint(f);
    x += 0x7fffu + ((x >> 16) & 1u);
    return (unsigned short)(x >> 16);
}
// packed 2x f32 -> bf16x2 in one instruction where available (gfx950: v_cvt_pk_bf16_f32)
__device__ __forceinline__ unsigned int f2bf2(float a, float b) {
#if __has_builtin(__builtin_amdgcn_cvt_pk_bf16_f32)
    auto r = __builtin_amdgcn_cvt_pk_bf16_f32(a, b);
    unsigned int u;
    __builtin_memcpy(&u, &r, 4);
    return u;
#else
    return (unsigned int)f2bf(a) | ((unsigned int)f2bf(b) << 16);
#endif
}

using frag_ab = __attribute__((ext_vector_type(8))) short;  // 8 bf16 = 4 VGPRs
using frag_cd = __attribute__((ext_vector_type(4))) float;
typedef _Float16 f16x8 __attribute__((ext_vector_type(8))); // 8 f16 = 4 VGPRs

#define TWST 72   // transform weight LDS stride (bf16)
#define THST 200  // transform h/y1 LDS stride (bf16)

// ---------------- fused transform: x[n,0:96] = W2g·prelu(W1g·h[n]+b1)+b2, grouped, MFMA ----------------
__global__ __launch_bounds__(256) void transform_mfma(
    const float* __restrict__ h,
    const float* __restrict__ tpw1, const float* __restrict__ tpb1, const float* __restrict__ tpa,
    const float* __restrict__ tpw2, const float* __restrict__ tpb2,
    const float* __restrict__ tmw1, const float* __restrict__ tmb1, const float* __restrict__ tma,
    const float* __restrict__ tmw2, const float* __restrict__ tmb2,
    float* __restrict__ xout, _Float16* __restrict__ xh)
{
    __shared__ alignas(16) unsigned short W1s[192 * TWST]; // [o][i] bf16
    __shared__ alignas(16) unsigned short W2s[96 * TWST];  // [o][i] bf16
    __shared__ alignas(16) unsigned short hs[64 * THST];   // [m][c] bf16; y1 overwrites in place
    __shared__ float b1s[192];
    __shared__ float b2s[96];

    const int tid = threadIdx.x;
    const int s = blockIdx.y;
    const float* w1 = s ? tmw1 : tpw1;
    const float* b1 = s ? tmb1 : tpb1;
    const float* w2 = s ? tmw2 : tpw2;
    const float* b2 = s ? tmb2 : tpb2;
    const float alpha = (s ? tma : tpa)[0];

    #pragma unroll
    for (int r = 0; r < 12; r++) {
        int idx4 = r * 256 + tid;                    // over 192*16
        int o = idx4 >> 4, i4 = (idx4 & 15) * 4;
        const float4 a = *(const float4*)&w1[o * 64 + i4];
        *(uint2*)&W1s[o * TWST + i4] = make_uint2(f2bf2(a.x, a.y), f2bf2(a.z, a.w));
    }
    #pragma unroll
    for (int r = 0; r < 6; r++) {
        int idx4 = r * 256 + tid;                    // over 96*16
        int o = idx4 >> 4, i4 = (idx4 & 15) * 4;
        const float4 a = *(const float4*)&w2[o * 64 + i4];
        *(uint2*)&W2s[o * TWST + i4] = make_uint2(f2bf2(a.x, a.y), f2bf2(a.z, a.w));
    }
    if (tid < 192) b1s[tid] = b1[tid];
    if (tid < 96) b2s[tid] = b2[tid];
    __syncthreads();

    const int lane = tid & 63;
    const int wv = tid >> 6;
    const int quad = lane >> 4;
    const int lcol = lane & 15;
    const int m0 = wv * 16;
    const int j0 = blockIdx.x * 64;

    #pragma unroll
    for (int r = 0; r < 12; r++) {
        int idx = r * 256 + tid;                     // over 64*48 float4s
        int m = idx / 48, q = idx - m * 48;
        const float4 a = *(const float4*)&h[(2 * (j0 + m) + s) * 192 + q * 4];
        *(uint2*)&hs[m * THST + q * 4] = make_uint2(f2bf2(a.x, a.y), f2bf2(a.z, a.w));
    }
    __syncthreads();

    const int arow = (m0 + lcol) * THST;
    #pragma unroll
    for (int g = 0; g < 3; g++) {
        frag_cd acc[4];
        #pragma unroll
        for (int nt = 0; nt < 4; nt++) acc[nt] = (frag_cd){0.f, 0.f, 0.f, 0.f};
        #pragma unroll
        for (int kt = 0; kt < 2; kt++) {
            const int k0 = kt * 32 + quad * 8;
            frag_ab af = *(const frag_ab*)&hs[arow + g * 64 + k0];
            #pragma unroll
            for (int nt = 0; nt < 4; nt++) {
                frag_ab bf = *(const frag_ab*)&W1s[(g * 64 + nt * 16 + lcol) * TWST + k0];
                acc[nt] = __builtin_amdgcn_mfma_f32_16x16x32_bf16(af, bf, acc[nt], 0, 0, 0);
            }
        }
        #pragma unroll
        for (int nt = 0; nt < 4; nt++) {
            const int o = g * 64 + nt * 16 + lcol;
            const float bv = b1s[o];
            #pragma unroll
            for (int reg = 0; reg < 4; reg++) {
                float u = acc[nt][reg] + bv;
                u = u >= 0.f ? u : alpha * u;
                hs[(m0 + quad * 4 + reg) * THST + o] = f2bf(u);
            }
        }
    }
    #pragma unroll
    for (int g2 = 0; g2 < 3; g2++) {
        frag_cd acc[2];
        acc[0] = (frag_cd){0.f, 0.f, 0.f, 0.f};
        acc[1] = (frag_cd){0.f, 0.f, 0.f, 0.f};
        #pragma unroll
        for (int kt = 0; kt < 2; kt++) {
            const int k0 = kt * 32 + quad * 8;
            frag_ab af = *(const frag_ab*)&hs[arow + g2 * 64 + k0];
            #pragma unroll
            for (int nt = 0; nt < 2; nt++) {
                frag_ab bf = *(const frag_ab*)&W2s[(g2 * 32 + nt * 16 + lcol) * TWST + k0];
                acc[nt] = __builtin_amdgcn_mfma_f32_16x16x32_bf16(af, bf, acc[nt], 0, 0, 0);
            }
        }
        #pragma unroll
        for (int nt = 0; nt < 2; nt++) {
            const int o2 = g2 * 32 + nt * 16 + lcol;
            const float bv = b2s[o2];
            #pragma unroll
            for (int reg = 0; reg < 4; reg++) {
                const int node = 2 * (j0 + m0 + quad * 4 + reg) + s;
                const float v = acc[nt][reg] + bv;
                xout[node * 96 + o2] = v;
                xh[node * 96 + o2] = (_Float16)v;
            }
        }
    }
}

// ---------------- gate device body (round-5 proven structure, f16 frag-major weights in LDS) ----------------
// gid = 256-edge group id; processes 4 x 64-edge tiles. W1f LDS already staged by caller.
// NOTE: LDS staging is essential — reading W1 fragments from global costs +68 VGPR (compiler
// keeps in-flight loads live) and halves occupancy (round-11 regression: 50->70us).
template<bool DUAL>
__device__ __forceinline__ void gate_body(
    const _Float16* __restrict__ xh, const _Float16* __restrict__ W1f,
    const int* __restrict__ srcp, const int* __restrict__ dstp,
    const int* __restrict__ mapA,
    const float* __restrict__ gb1, const float* __restrict__ ga,
    const float* __restrict__ gW2, const float* __restrict__ gb2,
    int layerA, int layerB, int gid,
    float* __restrict__ outA, float* __restrict__ outB)
{
    const int tid  = threadIdx.x;
    const int lane = tid & 63;
    const int wv   = tid >> 6;
    const int quad = lane >> 4;
    const int lcol = lane & 15;
    const int m0   = wv * 16;
    const int erow = m0 + lcol;
    const int koff = quad * 8;

    // tile-invariant per-lane W2/b1 (indexed by o = nt*16+lcol)
    float w2A[6], b1A[6], w2B[6], b1B[6];
    #pragma unroll
    for (int nt = 0; nt < 6; nt++) {
        w2A[nt] = gW2[layerA * 96 + nt * 16 + lcol];
        b1A[nt] = gb1[layerA * 96 + nt * 16 + lcol];
        if (DUAL) {
            w2B[nt] = gW2[layerB * 96 + nt * 16 + lcol];
            b1B[nt] = gb1[layerB * 96 + nt * 16 + lcol];
        }
    }
    const float alphaA = ga[layerA];
    const float b2A = gb2[layerA];
    const float alphaB = DUAL ? ga[layerB] : 0.f;
    const float b2B = DUAL ? gb2[layerB] : 0.f;

    // slot indices for this lane's edge in each of the 4 group-contiguous tiles
    int si[4], di[4];
    #pragma unroll
    for (int t = 0; t < 4; t++) {
        const int s = gid * 256 + t * 64 + erow;
        si[t] = srcp[s];
        di[t] = dstp[s];
    }
    __syncthreads();

    // preload tile 0's six 16B row chunks
    f16x8 A0, A1, A2, B0, B1, B2;
    {
        const _Float16* rs = xh + si[0] * 96 + koff;
        const _Float16* rd = xh + di[0] * 96 + koff;
        A0 = *(const f16x8*)rs;        B0 = *(const f16x8*)rd;
        A1 = *(const f16x8*)(rs + 32); B1 = *(const f16x8*)(rd + 32);
        A2 = *(const f16x8*)(rs + 64); B2 = *(const f16x8*)(rd + 64);
    }

    #pragma unroll
    for (int t = 0; t < 4; t++) {
        // products (v_pk_mul_f16) = this tile's A-fragments
        f16x8 p0 = A0 * B0;
        f16x8 p1 = A1 * B1;
        f16x8 p2 = A2 * B2;
        // issue next tile's gathers before the MFMA cluster (latency hides under compute)
        if (t < 3) {
            const _Float16* rs = xh + si[t + 1] * 96 + koff;
            const _Float16* rd = xh + di[t + 1] * 96 + koff;
            A0 = *(const f16x8*)rs;        B0 = *(const f16x8*)rd;
            A1 = *(const f16x8*)(rs + 32); B1 = *(const f16x8*)(rd + 32);
            A2 = *(const f16x8*)(rs + 64); B2 = *(const f16x8*)(rd + 64);
        }

        frag_cd accA[6], accB[6];
        #pragma unroll
        for (int nt = 0; nt < 6; nt++) {
            accA[nt] = (frag_cd){0.f, 0.f, 0.f, 0.f};
            if (DUAL) accB[nt] = (frag_cd){0.f, 0.f, 0.f, 0.f};
        }
        __builtin_amdgcn_s_setprio(1);
        #pragma unroll
        for (int kt = 0; kt < 3; kt++) {
            const f16x8 pk = (kt == 0) ? p0 : (kt == 1 ? p1 : p2);
            #pragma unroll
            for (int nt = 0; nt < 6; nt++) {
                const int f = ((nt * 3 + kt) * 4 + quad) * 16 + lcol;
                f16x8 bfragA = *(const f16x8*)&W1f[f * 8];
                accA[nt] = __builtin_amdgcn_mfma_f32_16x16x32_f16(pk, bfragA, accA[nt], 0, 0, 0);
                if (DUAL) {
                    f16x8 bfragB = *(const f16x8*)&W1f[9216 + f * 8];
                    accB[nt] = __builtin_amdgcn_mfma_f32_16x16x32_f16(pk, bfragB, accB[nt], 0, 0, 0);
                }
            }
        }
        __builtin_amdgcn_s_setprio(0);
        // phase 3: +b1, prelu, dot W2 (registers). C/D: col=lcol (o), row=quad*4+reg (edge).
        float psA[4] = {0.f, 0.f, 0.f, 0.f};
        float psB[4] = {0.f, 0.f, 0.f, 0.f};
        #pragma unroll
        for (int nt = 0; nt < 6; nt++) {
            #pragma unroll
            for (int reg = 0; reg < 4; reg++) {
                float u = accA[nt][reg] + b1A[nt];
                u = u >= 0.f ? u : alphaA * u;
                psA[reg] += u * w2A[nt];
            }
            if (DUAL) {
                #pragma unroll
                for (int reg = 0; reg < 4; reg++) {
                    float u = accB[nt][reg] + b1B[nt];
                    u = u >= 0.f ? u : alphaB * u;
                    psB[reg] += u * w2B[nt];
                }
            }
        }
        // shortened reduce over lcol: 2 stages x 4 regs -> reg-select (lcol&3) -> 2 stages x 1
        #pragma unroll
        for (int off = 1; off < 4; off <<= 1) {
            #pragma unroll
            for (int reg = 0; reg < 4; reg++) {
                psA[reg] += __shfl_xor(psA[reg], off, 64);
                if (DUAL) psB[reg] += __shfl_xor(psB[reg], off, 64);
            }
        }
        float vA = (lcol & 2) ? ((lcol & 1) ? psA[3] : psA[2])
                              : ((lcol & 1) ? psA[1] : psA[0]);
        vA += __shfl_xor(vA, 4, 64);
        vA += __shfl_xor(vA, 8, 64);
        float vB = 0.f;
        if (DUAL) {
            vB = (lcol & 2) ? ((lcol & 1) ? psB[3] : psB[2])
                            : ((lcol & 1) ? psB[1] : psB[0]);
            vB += __shfl_xor(vB, 4, 64);
            vB += __shfl_xor(vB, 8, 64);
        }
        // tanh on all lanes (no divergence); 16 lanes store (4B each, quad-consecutive)
        const float eA = tanhf(vA + b2A);
        const float eB = DUAL ? tanhf(vB + b2B) : 0.f;
        if (lcol < 4) {
            const int slot = gid * 256 + t * 64 + m0 + quad * 4 + lcol;
            outA[mapA ? mapA[slot] : slot] = eA;
            if (DUAL) outB[slot] = eB;
        }
    }
}

// ---------------- gate kernel: stage frag-major f16 W1 via uint4 copies, then body ----------------
template<bool DUAL>
__global__ __launch_bounds__(256) void gate_kernel(
    const _Float16* __restrict__ xh,
    const int* __restrict__ srcp, const int* __restrict__ dstp,
    const int* __restrict__ mapA,
    const _Float16* __restrict__ gw1f, const float* __restrict__ gb1,
    const float* __restrict__ ga,  const float* __restrict__ gW2,
    const float* __restrict__ gb2, int layerA, int layerB,
    float* __restrict__ outA, float* __restrict__ outB)
{
    __shared__ alignas(16) _Float16 W1f[(DUAL ? 2 : 1) * 9216];
    const int tid = threadIdx.x;
    {
        const uint4* g4 = (const uint4*)(gw1f + layerA * 9216);
        uint4* l4 = (uint4*)W1f;
        for (int i = tid; i < 1152; i += 256) l4[i] = g4[i];
        if (DUAL) {
            const uint4* h4 = (const uint4*)(gw1f + layerB * 9216);
            for (int i = tid; i < 1152; i += 256) l4[1152 + i] = h4[i];
        }
    }
    gate_body<DUAL>(xh, W1f, srcp, dstp, mapA, gb1, ga, gW2, gb2,
                    layerA, layerB, blockIdx.x, outA, outB);
}

// ---------------- CSR build: count / scan / scatter ----------------
__global__ __launch_bounds__(256) void count_kernel(
    const int* __restrict__ dst, int* __restrict__ cnt)
{
    int e = blockIdx.x * 256 + threadIdx.x;          // over E, exact
    atomicAdd(&cnt[dst[e]], 1);
}

// single block, 1024 threads; 25600 = 1024 * 25
__global__ __launch_bounds__(1024) void scan_kernel(
    const int* __restrict__ cnt, int* __restrict__ off, int* __restrict__ cur)
{
    __shared__ int part[1024];
    const int tid = threadIdx.x;
    const int base = tid * 25;
    int loc[25];
    int s = 0;
    #pragma unroll
    for (int i = 0; i < 25; i++) { loc[i] = s; s += cnt[base + i]; }
    part[tid] = s;
    __syncthreads();
    for (int d = 1; d < 1024; d <<= 1) {
        int t = (tid >= d) ? part[tid - d] : 0;
        __syncthreads();
        part[tid] += t;
        __syncthreads();
    }
    const int basesum = part[tid] - s;
    #pragma unroll
    for (int i = 0; i < 25; i++) {
        int o = basesum + loc[i];
        off[base + i] = o;
        cur[base + i] = o;
    }
    if (tid == 1023) off[N_NODES] = part[1023];
}

// also emits slot-ordered srcp/dstp so the gate and agg skip the perm indirection
__global__ __launch_bounds__(256) void scatter_kernel(
    const int* __restrict__ dst, const int* __restrict__ src,
    int* __restrict__ cur, int* __restrict__ perm,
    int* __restrict__ srcp, int* __restrict__ dstp)
{
    int e = blockIdx.x * 256 + threadIdx.x;          // over E, exact
    int d = dst[e];
    int p = atomicAdd(&cur[d], 1);
    perm[p] = e;
    srcp[p] = src[e];
    dstp[p] = d;
}

// ---------------- prep: t2wf = frag-major f16 transpose of t2w ----------------
__global__ __launch_bounds__(256) void prep_t2w(
    const float* __restrict__ t2w, _Float16* __restrict__ t2wf)
{
    int idx = blockIdx.x * 256 + threadIdx.x;        // over 36864, exact (144 blocks)
    int j = idx & 7;
    int t = idx >> 3;
    int lc = t & 15;
    int u = t >> 4;
    int c = u % 36, nt = u / 36;
    int o = nt * 16 + lc;
    int ck = c / 12, r = c - ck * 12;
    int kt3 = r >> 2, quad = r & 3;
    int k = ck * 96 + kt3 * 32 + quad * 8 + j;
    t2wf[idx] = (_Float16)t2w[k * 128 + o];
}

// ---------------- prep: gw1f = frag-major f16 gate W1 for both layers ----------------
__global__ __launch_bounds__(256) void prep_gw1(
    const float* __restrict__ gW1, _Float16* __restrict__ gw1f)
{
    int idx = blockIdx.x * 256 + threadIdx.x;        // over 2*9216, exact (72 blocks)
    int layer = idx / 9216;
    int rem = idx - layer * 9216;
    int fi = rem >> 3, j = rem & 7;
    int lc = fi & 15, r = fi >> 4;
    int quad = r & 3, t3 = r >> 2;
    int nt = t3 / 3, kt = t3 - nt * 3;
    int n = nt * 16 + lc, k0 = kt * 32 + quad * 8;
    gw1f[idx] = (_Float16)gW1[layer * 9216 + (k0 + j) * 96 + n];
}

// ---------------- fused: z = segsum(x[src]*e, dst) ; x_next = prelu(BN(LN(z + xin))) ----------------
// Gathers the f16 mirror xg (192B rows); residual xin stays f32; all accumulation f32.
// 8 independent gather chains in flight. Wave butterflies + 2-slot LDS combine (2 barriers).
__global__ __launch_bounds__(128) void agg_norm_kernel(
    const _Float16* __restrict__ xg, const int* __restrict__ srcp,
    const float* __restrict__ ef,
    const int* __restrict__ off,
    const float* __restrict__ xin,
    const float* __restrict__ lng, const float* __restrict__ lnb,
    const float* __restrict__ bng, const float* __restrict__ bnb,
    const float* __restrict__ bnrm, const float* __restrict__ bnrv,
    const float* __restrict__ acta, int layer,
    float* __restrict__ xout, _Float16* __restrict__ xh)
{
    __shared__ float red[4];                 // [0..1]=per-wave sum, [2..3]=per-wave var
    const int n = blockIdx.x;
    const int tid = threadIdx.x;
    const int wv = tid >> 6;
    const int beg = off[n], end = off[n + 1];
    float v = 0.f;
    if (tid < 96) {
        float v0 = 0.f, v1 = 0.f, v2 = 0.f, v3 = 0.f;
        float v4 = 0.f, v5 = 0.f, v6 = 0.f, v7 = 0.f;
        int j = beg;
        for (; j + 8 <= end; j += 8) {
            v0 += (float)xg[srcp[j]     * 96 + tid] * ef[j];
            v1 += (float)xg[srcp[j + 1] * 96 + tid] * ef[j + 1];
            v2 += (float)xg[srcp[j + 2] * 96 + tid] * ef[j + 2];
            v3 += (float)xg[srcp[j + 3] * 96 + tid] * ef[j + 3];
            v4 += (float)xg[srcp[j + 4] * 96 + tid] * ef[j + 4];
            v5 += (float)xg[srcp[j + 5] * 96 + tid] * ef[j + 5];
            v6 += (float)xg[srcp[j + 6] * 96 + tid] * ef[j + 6];
            v7 += (float)xg[srcp[j + 7] * 96 + tid] * ef[j + 7];
        }
        for (; j < end; j++) {
            v0 += (float)xg[srcp[j] * 96 + tid] * ef[j];
        }
        v = (((v0 + v1) + (v2 + v3)) + ((v4 + v5) + (v6 + v7))) + xin[n * 96 + tid];
    }
    float r = v;
    #pragma unroll
    for (int o2 = 1; o2 < 64; o2 <<= 1) r += __shfl_xor(r, o2, 64);
    if ((tid & 63) == 0) red[wv] = r;
    __syncthreads();
    const float mean = (red[0] + red[1]) * (1.f / 96.f);
    const float d = (tid < 96) ? (v - mean) : 0.f;
    float r2 = d * d;
    #pragma unroll
    for (int o2 = 1; o2 < 64; o2 <<= 1) r2 += __shfl_xor(r2, o2, 64);
    if ((tid & 63) == 0) red[2 + wv] = r2;
    __syncthreads();
    const float rstd = rsqrtf((red[2] + red[3]) * (1.f / 96.f) + EPSV);
    if (tid < 96) {
        const int c = layer * 96 + tid;
        float y = d * rstd * lng[c] + lnb[c];
        y = (y - bnrm[c]) * rsqrtf(bnrv[c] + EPSV) * bng[c] + bnb[c];
        const float a = acta[layer];
        const float o = y >= 0.f ? y : a * y;
        if (xout) xout[n * 96 + tid] = o;
        xh[n * 96 + tid] = (_Float16)o;
    }
}

// ---------------- final device body: out[64-node tile] = hcat @ t2_w + t2_b (MFMA, K=288) ----------------
__device__ __forceinline__ void final_body(
    const _Float16* __restrict__ xh0, const _Float16* __restrict__ xh1,
    const _Float16* __restrict__ xh2, const _Float16* __restrict__ t2wf,
    const float* __restrict__ t2b, float* __restrict__ out, int bid)
{
    const int tid  = threadIdx.x;
    const int lane = tid & 63;
    const int wv   = tid >> 6;
    const int quad = lane >> 4;
    const int lcol = lane & 15;
    const int mrow = bid * 64 + wv * 16 + lcol;

    frag_cd acc[8];
    #pragma unroll
    for (int nt = 0; nt < 8; nt++) acc[nt] = (frag_cd){0.f, 0.f, 0.f, 0.f};

    #pragma unroll
    for (int ck = 0; ck < 3; ck++) {
        const _Float16* xc = (ck == 0) ? xh0 : (ck == 1 ? xh1 : xh2);
        const _Float16* ap = xc + mrow * 96 + quad * 8;
        #pragma unroll
        for (int kt3 = 0; kt3 < 3; kt3++) {
            f16x8 afrag = *(const f16x8*)(ap + kt3 * 32);
            const int chunk = 12 * ck + 4 * kt3 + quad;
            #pragma unroll
            for (int nt = 0; nt < 8; nt++) {
                f16x8 bfrag = *(const f16x8*)&t2wf[((nt * 36 + chunk) * 16 + lcol) * 8];
                acc[nt] = __builtin_amdgcn_mfma_f32_16x16x32_f16(afrag, bfrag, acc[nt], 0, 0, 0);
            }
        }
    }
    const int node = bid * 64 + wv * 16 + quad * 4;
    #pragma unroll
    for (int nt = 0; nt < 8; nt++) {
        const int o = nt * 16 + lcol;
        const float bias = t2b[o];
        #pragma unroll
        for (int reg = 0; reg < 4; reg++)
            out[(node + reg) * 128 + o] = acc[nt][reg] + bias;
    }
}

// ---------------- fused tail: gate(layer1 es -> ee1) interleaved 4:1 with final readout ----------------
__global__ __launch_bounds__(256) void gate_final_kernel(
    const _Float16* __restrict__ xh0, const _Float16* __restrict__ xh1,
    const _Float16* __restrict__ xh2,
    const int* __restrict__ srcp, const int* __restrict__ dstp,
    const int* __restrict__ perm,
    const _Float16* __restrict__ gw1f, const float* __restrict__ gb1,
    const float* __restrict__ ga,  const float* __restrict__ gW2,
    const float* __restrict__ gb2,
    const _Float16* __restrict__ t2wf, const float* __restrict__ t2b,
    float* __restrict__ ee1, float* __restrict__ out)
{
    __shared__ alignas(16) _Float16 W1f[9216];
    const int g = blockIdx.x / 5;
    const int pos = blockIdx.x - g * 5;
    if (pos < 4) {
        const int tid = threadIdx.x;
        const uint4* g4 = (const uint4*)(gw1f + 9216);   // layer 1
        uint4* l4 = (uint4*)W1f;
        for (int i = tid; i < 1152; i += 256) l4[i] = g4[i];
        gate_body<false>(xh2, W1f, srcp, dstp, perm, gb1, ga, gW2, gb2,
                         1, 0, g * 4 + pos, ee1, nullptr);
    } else {
        final_body(xh0, xh1, xh2, t2wf, t2b, out, g);
    }
}

extern "C" void kernel_launch(void* const* d_in, const int* in_sizes, int n_in,
                              void* d_out, int out_size, void* d_ws, size_t ws_size,
                              hipStream_t stream)
{
    const float* h    = (const float*)d_in[0];
    const int*   src  = (const int*)d_in[1];
    const int*   dst  = (const int*)d_in[2];
    const float* tpw1 = (const float*)d_in[3];
    const float* tpb1 = (const float*)d_in[4];
    const float* tpa  = (const float*)d_in[5];
    const float* tpw2 = (const float*)d_in[6];
    const float* tpb2 = (const float*)d_in[7];
    const float* tmw1 = (const float*)d_in[8];
    const float* tmb1 = (const float*)d_in[9];
    const float* tma  = (const float*)d_in[10];
    const float* tmw2 = (const float*)d_in[11];
    const float* tmb2 = (const float*)d_in[12];
    const float* lng  = (const float*)d_in[13];
    const float* lnb  = (const float*)d_in[14];
    const float* bng  = (const float*)d_in[15];
    const float* bnb  = (const float*)d_in[16];
    const float* bnrm = (const float*)d_in[17];
    const float* bnrv = (const float*)d_in[18];
    const float* acta = (const float*)d_in[19];
    const float* gW1  = (const float*)d_in[20];
    const float* gb1  = (const float*)d_in[21];
    const float* ga   = (const float*)d_in[22];
    const float* gW2  = (const float*)d_in[23];
    const float* gb2  = (const float*)d_in[24];
    const float* t2w  = (const float*)d_in[25];
    const float* t2b  = (const float*)d_in[26];

    // workspace layout: byte-identical footprint to the round-2/5/8/9/10 passing layout (~41.27 MB).
    float* ws = (float*)d_ws;
    float* x0 = ws;                         // N*96 f32 (agg0 residual)
    float* x1 = x0 + N_NODES * 96;          // N*96 f32 (agg1 residual)
    float* eb = x1 + N_NODES * 96;          // E f32 (slot order)
    _Float16* xh0 = (_Float16*)(eb + N_EDGES);      // N*96 f16 mirror (stage 0)
    _Float16* xh1 = xh0 + N_NODES * 96;             // N*96 f16 mirror (stage 1)
    _Float16* xh2 = xh1 + N_NODES * 96;             // N*96 f16 mirror (stage 2)
    int* cnt  = (int*)(xh2 + N_NODES * 96); // N   (dead after scatter)
    int* off  = cnt + N_NODES;              // N+1
    int* cur  = off + N_NODES + 1;          // N   (dead after scatter)
    int* perm = cur + N_NODES;              // E   (slot -> original edge)
    int* srcp = perm + N_EDGES;             // E   (slot-ordered src)
    int* dstp = srcp + N_EDGES;             // E   (slot-ordered dst)
    // t2wf aliases cnt (73,728 B < 102,400 B), gw1f aliases cur (36,864 B < 102,400 B):
    // both written AFTER scatter_kernel, when cnt/cur are dead. Stream order guarantees safety.
    _Float16* t2wf = (_Float16*)cnt;        // 36864 f16 (frag-major readout weight)
    _Float16* gw1f = (_Float16*)cur;        // 2*9216 f16 (frag-major gate W1, both layers)

    float* out = (float*)d_out;             // N*128 fp32
    float* ee  = out + N_NODES * 128;       // 2E fp32

    // ---- CSR build (dst-only; used by gate + agg_norm) ----
    hipMemsetAsync(cnt, 0, N_NODES * sizeof(int), stream);
    count_kernel<<<N_EDGES / 256, 256, 0, stream>>>(dst, cnt);
    scan_kernel<<<1, 1024, 0, stream>>>(cnt, off, cur);
    scatter_kernel<<<N_EDGES / 256, 256, 0, stream>>>(dst, src, cur, perm, srcp, dstp);
    // cnt/cur now dead -> reuse for prepped weights
    prep_t2w<<<144, 256, 0, stream>>>(t2w, t2wf);
    prep_gw1<<<72, 256, 0, stream>>>(gW1, gw1f);

    // ---- fused transform (t1+t2): x0 fp32 + xh0 = f16(x0) ----
    transform_mfma<<<dim3(200, 2), 256, 0, stream>>>(
        h, tpw1, tpb1, tpa, tpw2, tpb2, tmw1, tmb1, tma, tmw2, tmb2, x0, xh0);

    // ---- layer 0 ----
    gate_kernel<false><<<1600, 256, 0, stream>>>(xh0, srcp, dstp, nullptr,
        gw1f, gb1, ga, gW2, gb2, 0, 0, eb, nullptr);
    agg_norm_kernel<<<N_NODES, 128, 0, stream>>>(xh0, srcp, eb, off, x0,
        lng, lnb, bng, bnb, bnrm, bnrv, acta, 0, x1, xh1);  // gather f16 xh0; residual f32 x0

    // ---- fused: es[layer0](x1) -> ee (orig order)  AND  agg-gate[layer1](x1) -> eb (slot order) ----
    gate_kernel<true><<<1600, 256, 0, stream>>>(xh1, srcp, dstp, perm,
        gw1f, gb1, ga, gW2, gb2, 0, 1, ee, eb);

    // ---- layer 1 ----
    agg_norm_kernel<<<N_NODES, 128, 0, stream>>>(xh1, srcp, eb, off, x1,
        lng, lnb, bng, bnb, bnrm, bnrv, acta, 1, nullptr, xh2);  // gather f16 xh1; residual f32 x1

    // ---- fused tail: es[layer1](xh2) -> ee+E  interleaved with readout ----
    gate_final_kernel<<<2000, 256, 0, stream>>>(xh0, xh1, xh2, srcp, dstp, perm,
        gw1f, gb1, ga, gW2, gb2, t2wf, t2b, ee + N_EDGES, out);
}